// Round 7
// baseline (293.747 us; speedup 1.0000x reference)
//
#include <hip/hip_runtime.h>
#include <hip/hip_bf16.h>
#include <cstddef>

// ---------------------------------------------------------------------------
// 2-layer GCN: h1 = x@W1; hmid = relu(Agg(h1) + b1); h2 = hmid@W2;
// out = Agg(h2) + b2.  Agg = sym-normalized scatter-add with self-loops.
// R1-R5: multi-block scan, bf16 h, 4B CSR, MFMA GEMMs, gemm2 fused into agg1.
// R6 (this): 10 launches -> 4. `mega` kernel runs gemm1 CONCURRENTLY with
//   count -> decoupled-lookback scan -> fill, linked by device-scope flag
//   handshakes (atomics at coherent point + threadfence_system + scoped
//   loads). ~11 us/launch gap * 6 removed launches is the target.
// ---------------------------------------------------------------------------

typedef __attribute__((ext_vector_type(8))) short short8;
typedef __attribute__((ext_vector_type(4))) float f32x4;
typedef unsigned long long u64;

__device__ inline unsigned short f2bf(float f) {
    __hip_bfloat16 b = __float2bfloat16(f);
    return *reinterpret_cast<unsigned short*>(&b);
}
__device__ inline float bf2f_lo(unsigned int u) {
    unsigned int v = u << 16;
    return *reinterpret_cast<float*>(&v);
}
__device__ inline float bf2f_hi(unsigned int u) {
    unsigned int v = u & 0xffff0000u;
    return *reinterpret_cast<float*>(&v);
}

__device__ inline u64 ld_acq64(u64* p) {
    return __hip_atomic_load(p, __ATOMIC_ACQUIRE, __HIP_MEMORY_SCOPE_AGENT);
}
__device__ inline void st_rel64(u64* p, u64 v) {
    __hip_atomic_store(p, v, __ATOMIC_RELEASE, __HIP_MEMORY_SCOPE_AGENT);
}
__device__ inline int ld_acq32(int* p) {
    return __hip_atomic_load(p, __ATOMIC_ACQUIRE, __HIP_MEMORY_SCOPE_AGENT);
}

// ---------------------------------------------------------------------------
// init: W1/W2 -> global MFMA-B fragment order (bf16); zero deg, lookback
// state, and flags. One launch, all independent work.
// ---------------------------------------------------------------------------
__global__ __launch_bounds__(256) void init_kernel(const float* __restrict__ W1,
                                                   const float* __restrict__ W2,
                                                   unsigned short* __restrict__ W1f,
                                                   unsigned short* __restrict__ W2f,
                                                   int* __restrict__ deg,
                                                   u64* __restrict__ lb,
                                                   int* __restrict__ flags, int N) {
    int idx = blockIdx.x * 256 + threadIdx.x;
    if (idx < N) deg[idx] = 0;
    if (idx < 64) lb[idx] = 0;
    if (idx < 4) flags[idx] = 0;
    if (idx < 3072) {
        const float* W;
        unsigned short* Wf;
        int n, oct, Nc;
        if (idx < 2048) { W = W1; Wf = W1f; Nc = 128; n = idx >> 4; oct = idx & 15; }
        else { W = W2; Wf = W2f; Nc = 64; int i2 = idx - 2048; n = i2 >> 4; oct = i2 & 15; }
        int k0 = oct * 8;
        int ks = k0 >> 5, quad = (k0 >> 3) & 3, ntg = n >> 4;
        short8 v;
        #pragma unroll
        for (int j = 0; j < 8; j++) v[j] = (short)f2bf(W[(k0 + j) * Nc + n]);
        int off = (((ntg * 4 + ks) * 64) + (n & 15) + 16 * quad) * 8;
        *(short8*)(Wf + off) = v;
    }
}

// ---------------------------------------------------------------------------
// mega: gemm1 || (count -> fill) || (lookback scan)
//   blocks [0, GB):        gemm1 (h1 = x @ W1, bf16 out)
//   blocks [GB, GB+CB):    count (grid-stride) -> flags[0]++; spin flags[1];
//                          fill (grid-stride, weights from deg)
//   blocks [GB+CB, +SB):   spin flags[0]==CB; one-pass scan w/ decoupled
//                          lookback -> offs/cur/dinv; flags[1]++
// Handshake safety: counters via device atomics; release = threadfence_system
// before flag bump (writes back local L2); acquire = threadfence_system after
// spin (invalidates local L1/L2). cur written with agent-scoped stores since
// fill RMWs it within this kernel.
// ---------------------------------------------------------------------------
#define MEGA_CB 256

__global__ __launch_bounds__(256) void mega_kernel(
    const float* __restrict__ x, const unsigned short* __restrict__ W1f,
    unsigned short* __restrict__ h1,
    const int* __restrict__ src, const int* __restrict__ dst, int E,
    int* __restrict__ deg, int N,
    u64* __restrict__ lb, int* __restrict__ offs, int* __restrict__ cur,
    float* __restrict__ dinv, unsigned int* __restrict__ csr,
    int* __restrict__ flags) {

    const int GB = (N + 63) / 64;
    const int CB = MEGA_CB;
    const int SB = (N + 1023) / 1024;
    int b = blockIdx.x;
    int tid = threadIdx.x;

    __shared__ unsigned short As[64 * 128];  // gemm1 staging (16 KB)
    __shared__ int ws[4];
    __shared__ int s_prefix;

    if (b < GB) {
        // ---------------- gemm1 ----------------
        constexpr int K = 128, BN = 128;
        int lane = tid & 63;
        int w = tid >> 6;
        int row0 = b * 64;

        short8 bfr[2][4];
        #pragma unroll
        for (int nl = 0; nl < 2; nl++)
            #pragma unroll
            for (int ks = 0; ks < 4; ks++)
                bfr[nl][ks] = *(const short8*)(W1f + ((((w * 2 + nl) * 4 + ks) * 64) + lane) * 8);

        #pragma unroll
        for (int it = 0; it < 8; it++) {
            int idx = it * 256 + tid;
            int row = idx >> 5, kq = idx & 31;
            int k0 = kq * 4;
            int ks = k0 >> 5, quad = (k0 >> 3) & 3, j0 = k0 & 7, mt = row >> 4;
            ushort4 o = make_ushort4(0, 0, 0, 0);
            int gr = row0 + row;
            if (gr < N) {
                float4 a = *(const float4*)(x + (size_t)gr * K + k0);
                o.x = f2bf(a.x); o.y = f2bf(a.y); o.z = f2bf(a.z); o.w = f2bf(a.w);
            }
            int off = (((mt * 4 + ks) * 64) + (row & 15) + 16 * quad) * 8 + j0;
            *(ushort4*)(As + off) = o;
        }
        __syncthreads();

        f32x4 acc[4][2];
        #pragma unroll
        for (int mt = 0; mt < 4; mt++)
            #pragma unroll
            for (int nl = 0; nl < 2; nl++) acc[mt][nl] = (f32x4){0.f, 0.f, 0.f, 0.f};

        #pragma unroll
        for (int ks = 0; ks < 4; ks++) {
            short8 af[4];
            #pragma unroll
            for (int mt = 0; mt < 4; mt++)
                af[mt] = *(const short8*)(As + (((mt * 4 + ks) * 64) + lane) * 8);
            #pragma unroll
            for (int mt = 0; mt < 4; mt++)
                #pragma unroll
                for (int nl = 0; nl < 2; nl++)
                    acc[mt][nl] = __builtin_amdgcn_mfma_f32_16x16x32_bf16(
                        af[mt], bfr[nl][ks], acc[mt][nl], 0, 0, 0);
        }

        int col16 = lane & 15;
        int rowq = lane >> 4;
        #pragma unroll
        for (int mt = 0; mt < 4; mt++) {
            #pragma unroll
            for (int nl = 0; nl < 2; nl++) {
                int gc = (w * 2 + nl) * 16 + col16;
                #pragma unroll
                for (int r = 0; r < 4; r++) {
                    int gr = row0 + mt * 16 + rowq * 4 + r;
                    if (gr < N) h1[(size_t)gr * BN + gc] = f2bf(acc[mt][nl][r]);
                }
            }
        }
        return;
    }

    if (b < GB + CB) {
        // ---------------- count -> fill ----------------
        int cb = b - GB;
        for (int i = cb * 256 + tid; i < E; i += CB * 256)
            atomicAdd(&deg[dst[i]], 1);
        __syncthreads();
        if (tid == 0) {
            __threadfence_system();            // release: counts visible
            atomicAdd(&flags[0], 1);
            while (ld_acq32(&flags[1]) < SB) __builtin_amdgcn_s_sleep(2);
            __threadfence_system();            // acquire: see cur/deg fresh
        }
        __syncthreads();
        for (int i = cb * 256 + tid; i < E; i += CB * 256) {
            int s = src[i];
            int d = dst[i];
            int p = atomicAdd(&cur[d], 1);
            float w = rsqrtf((float)((deg[s] + 1) * (deg[d] + 1)));
            csr[p] = (unsigned int)s | ((unsigned int)f2bf(w) << 16);
        }
        return;
    }

    // ---------------- scan (decoupled lookback) ----------------
    int sb = b - GB - CB;                      // 0..SB-1
    if (tid == 0) {
        while (ld_acq32(&flags[0]) < CB) __builtin_amdgcn_s_sleep(2);
        __threadfence_system();                // acquire: see deg fresh
    }
    __syncthreads();

    int lane = tid & 63;
    int wv = tid >> 6;
    int i = sb * 1024 + tid * 4;
    int v0 = (i + 0 < N) ? deg[i + 0] : 0;
    int v1 = (i + 1 < N) ? deg[i + 1] : 0;
    int v2 = (i + 2 < N) ? deg[i + 2] : 0;
    int v3 = (i + 3 < N) ? deg[i + 3] : 0;
    int tsum = v0 + v1 + v2 + v3;
    int xs = tsum;
    #pragma unroll
    for (int off = 1; off < 64; off <<= 1) {
        int y = __shfl_up(xs, off, 64);
        if (lane >= off) xs += y;
    }
    if (lane == 63) ws[wv] = xs;
    __syncthreads();
    int wprefix = 0;
    #pragma unroll
    for (int w2 = 0; w2 < 4; w2++) wprefix += (w2 < wv) ? ws[w2] : 0;
    int chunk_total = ws[0] + ws[1] + ws[2] + ws[3];

    if (tid == 0) {
        st_rel64(&lb[sb], ((u64)(unsigned)chunk_total << 2) | 1ull);
        int prefix = 0;
        for (int pred = sb - 1; pred >= 0; --pred) {
            u64 v;
            do {
                v = ld_acq64(&lb[pred]);
                if ((v & 3) == 0) __builtin_amdgcn_s_sleep(1);
            } while ((v & 3) == 0);
            prefix += (int)(unsigned)(v >> 2);
            if ((v & 3) == 2) break;
        }
        st_rel64(&lb[sb], ((u64)(unsigned)(prefix + chunk_total) << 2) | 2ull);
        s_prefix = prefix;
    }
    __syncthreads();

    int carry = s_prefix;
    int e0 = carry + wprefix + xs - tsum;
    int e1 = e0 + v0, e2 = e1 + v1, e3 = e2 + v2;
    if (i + 0 < N) {
        offs[i + 0] = e0;
        __hip_atomic_store(&cur[i + 0], e0, __ATOMIC_RELAXED, __HIP_MEMORY_SCOPE_AGENT);
        dinv[i + 0] = rsqrtf((float)(v0 + 1));
    }
    if (i + 1 < N) {
        offs[i + 1] = e1;
        __hip_atomic_store(&cur[i + 1], e1, __ATOMIC_RELAXED, __HIP_MEMORY_SCOPE_AGENT);
        dinv[i + 1] = rsqrtf((float)(v1 + 1));
    }
    if (i + 2 < N) {
        offs[i + 2] = e2;
        __hip_atomic_store(&cur[i + 2], e2, __ATOMIC_RELAXED, __HIP_MEMORY_SCOPE_AGENT);
        dinv[i + 2] = rsqrtf((float)(v2 + 1));
    }
    if (i + 3 < N) {
        offs[i + 3] = e3;
        __hip_atomic_store(&cur[i + 3], e3, __ATOMIC_RELAXED, __HIP_MEMORY_SCOPE_AGENT);
        dinv[i + 3] = rsqrtf((float)(v3 + 1));
    }
    if (sb == SB - 1 && tid == 0) offs[N] = carry + chunk_total;
    __syncthreads();
    if (tid == 0) {
        __threadfence_system();                // release: cur/offs/dinv visible
        atomicAdd(&flags[1], 1);
    }
}

// ---------------------------------------------------------------------------
// aggmm: fused Agg(layer1) + bias + ReLU + GEMM2 (h2 = hmid @ W2, bf16).
// Block = 4 waves = 16 nodes. 32 lanes/edge x 2 edges x unroll4; shfl_xor
// combine; rows -> LDS A-frag order; 4 MFMAs per wave.
// ---------------------------------------------------------------------------
__global__ __launch_bounds__(256) void aggmm_kernel(const unsigned short* __restrict__ h1,
                                                    const int* __restrict__ offs,
                                                    const unsigned int* __restrict__ csr,
                                                    const float* __restrict__ dinv,
                                                    const float* __restrict__ b1,
                                                    const unsigned short* __restrict__ W2f,
                                                    unsigned short* __restrict__ h2,
                                                    int n) {
    __shared__ unsigned short As[4 * 64 * 8];  // 4 KB, one 16x128 A-tile

    int tid = threadIdx.x;
    int t = tid & 63;
    int w = tid >> 6;
    int p = t >> 5;
    int t5 = t & 31;
    int nodebase = blockIdx.x * 16;

    short8 bw[4];
    #pragma unroll
    for (int ks = 0; ks < 4; ks++)
        bw[ks] = *(const short8*)(W2f + (((w * 4 + ks) * 64) + t) * 8);

    float4 bias = *(const float4*)(b1 + t5 * 4);

    #pragma unroll
    for (int i = 0; i < 4; i++) {
        int row16 = w * 4 + i;
        int node = nodebase + row16;
        float a0 = 0.f, a1 = 0.f, a2 = 0.f, a3 = 0.f;
        if (node < n) {
            float di = dinv[node];
            float sw = di * di;
            if (p == 0) {
                uint2 su = *(const uint2*)(h1 + (size_t)node * 128 + t5 * 4);
                a0 = bf2f_lo(su.x) * sw; a1 = bf2f_hi(su.x) * sw;
                a2 = bf2f_lo(su.y) * sw; a3 = bf2f_hi(su.y) * sw;
            }
            int e0 = offs[node];
            int e1 = offs[node + 1];
            int iters = (e1 - e0 + 7) >> 3;
            for (int it = 0; it < iters; it++) {
                int eb = e0 + it * 8;
                #pragma unroll
                for (int j = 0; j < 4; j++) {
                    int ee = eb + j * 2 + p;
                    int ec = min(ee, e1 - 1);
                    unsigned int pk = csr[ec];
                    float wgt = (ee < e1) ? bf2f_hi(pk) : 0.f;
                    int s = pk & 0xffff;
                    uint2 hu = *(const uint2*)(h1 + (size_t)s * 128 + t5 * 4);
                    a0 += bf2f_lo(hu.x) * wgt; a1 += bf2f_hi(hu.x) * wgt;
                    a2 += bf2f_lo(hu.y) * wgt; a3 += bf2f_hi(hu.y) * wgt;
                }
            }
        }
        a0 += __shfl_xor(a0, 32, 64);
        a1 += __shfl_xor(a1, 32, 64);
        a2 += __shfl_xor(a2, 32, 64);
        a3 += __shfl_xor(a3, 32, 64);
        if (p == 0) {
            if (node < n) {
                a0 = fmaxf(a0 + bias.x, 0.f);
                a1 = fmaxf(a1 + bias.y, 0.f);
                a2 = fmaxf(a2 + bias.z, 0.f);
                a3 = fmaxf(a3 + bias.w, 0.f);
            }
            int k0 = t5 * 4;
            int ks = k0 >> 5, quad = (k0 >> 3) & 3, j0 = k0 & 7;
            ushort4 pk4 = make_ushort4(f2bf(a0), f2bf(a1), f2bf(a2), f2bf(a3));
            *(ushort4*)(As + ((ks * 64) + row16 + 16 * quad) * 8 + j0) = pk4;
        }
    }
    __syncthreads();

    f32x4 acc = (f32x4){0.f, 0.f, 0.f, 0.f};
    #pragma unroll
    for (int ks = 0; ks < 4; ks++) {
        short8 af = *(const short8*)(As + ((ks * 64) + t) * 8);
        acc = __builtin_amdgcn_mfma_f32_16x16x32_bf16(af, bw[ks], acc, 0, 0, 0);
    }

    int col = w * 16 + (t & 15);
    int rowq = t >> 4;
    #pragma unroll
    for (int r = 0; r < 4; r++) {
        int gr = nodebase + rowq * 4 + r;
        if (gr < n) h2[(size_t)gr * 64 + col] = f2bf(acc[r]);
    }
}

// ---------------------------------------------------------------------------
// aggout: Agg(layer2) + bias, fp32 out. One node/wave; 16 lanes/edge,
// 4 edges concurrent, unroll2; shfl_xor(16,32) combine; float4 epilogue.
// ---------------------------------------------------------------------------
__global__ __launch_bounds__(256) void aggout_kernel(const unsigned short* __restrict__ h2,
                                                     const int* __restrict__ offs,
                                                     const unsigned int* __restrict__ csr,
                                                     const float* __restrict__ dinv,
                                                     const float* __restrict__ b2,
                                                     float* __restrict__ out, int n) {
    int tid = threadIdx.x;
    int t = tid & 63;
    int w = tid >> 6;
    int node = blockIdx.x * 4 + w;
    if (node >= n) return;
    int p = t >> 4;
    int t4 = t & 15;

    float a0 = 0.f, a1 = 0.f, a2 = 0.f, a3 = 0.f;
    float di = dinv[node];
    float sw = di * di;
    if (p == 0) {
        uint2 su = *(const uint2*)(h2 + (size_t)node * 64 + t4 * 4);
        a0 = bf2f_lo(su.x) * sw; a1 = bf2f_hi(su.x) * sw;
        a2 = bf2f_lo(su.y) * sw; a3 = bf2f_hi(su.y) * sw;
    }

    int e0 = offs[node];
    int e1 = offs[node + 1];
    int iters = (e1 - e0 + 7) >> 3;
    for (int it = 0; it < iters; it++) {
        int eb = e0 + it * 8;
        #pragma unroll
        for (int j = 0; j < 2; j++) {
            int ee = eb + j * 4 + p;
            int ec = min(ee, e1 - 1);
            unsigned int pk = csr[ec];
            float wgt = (ee < e1) ? bf2f_hi(pk) : 0.f;
            int s = pk & 0xffff;
            uint2 hu = *(const uint2*)(h2 + (size_t)s * 64 + t4 * 4);
            a0 += bf2f_lo(hu.x) * wgt; a1 += bf2f_hi(hu.x) * wgt;
            a2 += bf2f_lo(hu.y) * wgt; a3 += bf2f_hi(hu.y) * wgt;
        }
    }
    a0 += __shfl_xor(a0, 16, 64); a1 += __shfl_xor(a1, 16, 64);
    a2 += __shfl_xor(a2, 16, 64); a3 += __shfl_xor(a3, 16, 64);
    a0 += __shfl_xor(a0, 32, 64); a1 += __shfl_xor(a1, 32, 64);
    a2 += __shfl_xor(a2, 32, 64); a3 += __shfl_xor(a3, 32, 64);
    if (p == 0) {
        float4 bb = *(const float4*)(b2 + t4 * 4);
        *(float4*)(out + (size_t)node * 64 + t4 * 4) =
            make_float4(a0 + bb.x, a1 + bb.y, a2 + bb.z, a3 + bb.w);
    }
}

extern "C" void kernel_launch(void* const* d_in, const int* in_sizes, int n_in,
                              void* d_out, int out_size, void* d_ws, size_t ws_size,
                              hipStream_t stream) {
    const float* x  = (const float*)d_in[0];
    const int*   ei = (const int*)d_in[1];
    const float* W1 = (const float*)d_in[2];
    const float* b1 = (const float*)d_in[3];
    const float* W2 = (const float*)d_in[4];
    const float* b2 = (const float*)d_in[5];

    const int N = in_sizes[0] / 128;   // 50000
    const int E = in_sizes[1] / 2;     // 500000
    const int* src = ei;
    const int* dst = ei + E;

    char* p = (char*)d_ws;
    auto alloc = [&](size_t bytes) {
        char* r = p;
        p += (bytes + 255) & ~(size_t)255;
        return r;
    };
    int*   degi  = (int*)  alloc((size_t)N * 4);
    float* dinv  = (float*)alloc((size_t)N * 4);
    int*   offs  = (int*)  alloc((size_t)(N + 1) * 4);
    int*   cur   = (int*)  alloc((size_t)N * 4);
    u64*   lb    = (u64*)  alloc((size_t)64 * 8);
    int*   flags = (int*)  alloc((size_t)4 * 4);
    unsigned int*   csr  = (unsigned int*)alloc((size_t)E * 4);
    unsigned short* W1f  = (unsigned short*)alloc((size_t)128 * 128 * 2);
    unsigned short* W2f  = (unsigned short*)alloc((size_t)64 * 128 * 2);
    unsigned short* h1   = (unsigned short*)alloc((size_t)N * 128 * 2);
    unsigned short* h2   = (unsigned short*)alloc((size_t)N * 64 * 2);
    float* out = (float*)d_out;

    const int GB = (N + 63) / 64;        // 782
    const int SB = (N + 1023) / 1024;    // 49
    const int MEGA = GB + MEGA_CB + SB;  // 1087

    init_kernel<<<(N + 255) / 256, 256, 0, stream>>>(W1, W2, W1f, W2f, degi, lb, flags, N);
    mega_kernel<<<MEGA, 256, 0, stream>>>(x, W1f, h1, src, dst, E, degi, N,
                                          lb, offs, cur, dinv, csr, flags);
    aggmm_kernel<<<(N + 15) / 16, 256, 0, stream>>>(h1, offs, csr, dinv, b1, W2f, h2, N);
    aggout_kernel<<<(N + 3) / 4, 256, 0, stream>>>(h2, offs, csr, dinv, b2, out, N);
}

// Round 8
// 190.893 us; speedup vs baseline: 1.5388x; 1.5388x over previous
//
#include <hip/hip_runtime.h>
#include <hip/hip_bf16.h>
#include <cstddef>

// ---------------------------------------------------------------------------
// 2-layer GCN: h1 = x@W1; hmid = relu(Agg(h1) + b1); h2 = hmid@W2;
// out = Agg(h2) + b2.  Agg = sym-normalized scatter-add with self-loops.
// R1-R5: multi-block scan, bf16 h, 4B CSR, MFMA GEMMs, gemm2 fused into agg1.
// R6: 10 launches. R7 (FAILED, reverted): spin-fused mega kernel -- intra-
//   kernel producer/consumer sync (threadfence_system + agent-scope spins)
//   cost ~130 us. Kernel boundaries are the cheap sync on this chip.
// R8 (this): R6 structure, 10 -> 6 launches with NO dependent-phase spins:
//   init (zero+wt_frag), count, scan_lb (single-kernel decoupled lookback
//   among 49 peer blocks), fillgemm (fill || gemm1, independent block
//   ranges, zero handshake), aggmm, aggout.
// ---------------------------------------------------------------------------

typedef __attribute__((ext_vector_type(8))) short short8;
typedef __attribute__((ext_vector_type(4))) float f32x4;
typedef unsigned long long u64;

__device__ inline unsigned short f2bf(float f) {
    __hip_bfloat16 b = __float2bfloat16(f);
    return *reinterpret_cast<unsigned short*>(&b);
}
__device__ inline float bf2f_lo(unsigned int u) {
    unsigned int v = u << 16;
    return *reinterpret_cast<float*>(&v);
}
__device__ inline float bf2f_hi(unsigned int u) {
    unsigned int v = u & 0xffff0000u;
    return *reinterpret_cast<float*>(&v);
}
__device__ inline u64 ld_acq64(u64* p) {
    return __hip_atomic_load(p, __ATOMIC_ACQUIRE, __HIP_MEMORY_SCOPE_AGENT);
}
__device__ inline void st_rel64(u64* p, u64 v) {
    __hip_atomic_store(p, v, __ATOMIC_RELEASE, __HIP_MEMORY_SCOPE_AGENT);
}

// ---------------------------------------------------------------------------
// init: zero deg + lookback state; W1/W2 -> global MFMA-B fragment order.
// ---------------------------------------------------------------------------
__global__ __launch_bounds__(256) void init_kernel(const float* __restrict__ W1,
                                                   const float* __restrict__ W2,
                                                   unsigned short* __restrict__ W1f,
                                                   unsigned short* __restrict__ W2f,
                                                   int* __restrict__ deg,
                                                   u64* __restrict__ lb, int N) {
    int idx = blockIdx.x * 256 + threadIdx.x;
    if (idx < N) deg[idx] = 0;
    if (idx < 64) lb[idx] = 0;
    if (idx < 3072) {
        const float* W;
        unsigned short* Wf;
        int n, oct, Nc;
        if (idx < 2048) { W = W1; Wf = W1f; Nc = 128; n = idx >> 4; oct = idx & 15; }
        else { W = W2; Wf = W2f; Nc = 64; int i2 = idx - 2048; n = i2 >> 4; oct = i2 & 15; }
        int k0 = oct * 8;
        int ks = k0 >> 5, quad = (k0 >> 3) & 3, ntg = n >> 4;
        short8 v;
        #pragma unroll
        for (int j = 0; j < 8; j++) v[j] = (short)f2bf(W[(k0 + j) * Nc + n]);
        int off = (((ntg * 4 + ks) * 64) + (n & 15) + 16 * quad) * 8;
        *(short8*)(Wf + off) = v;
    }
}

__global__ __launch_bounds__(256) void count_kernel(const int* __restrict__ dst, int E,
                                                    int* __restrict__ deg) {
    int i = blockIdx.x * blockDim.x + threadIdx.x;
    if (i < E) atomicAdd(&deg[dst[i]], 1);
}

// ---------------------------------------------------------------------------
// scan_lb: one-pass exclusive scan of deg via decoupled lookback (SB=49
// peer blocks, all co-resident; spins only on peer lb[] entries).
// Writes offs, cur, dinv.
// ---------------------------------------------------------------------------
__global__ __launch_bounds__(256) void scan_lb_kernel(const int* __restrict__ deg, int N,
                                                      u64* __restrict__ lb,
                                                      int* __restrict__ offs,
                                                      int* __restrict__ cur,
                                                      float* __restrict__ dinv) {
    __shared__ int ws[4];
    __shared__ int s_prefix;
    int tid = threadIdx.x;
    int sb = blockIdx.x;
    int SB = gridDim.x;
    int lane = tid & 63;
    int wv = tid >> 6;

    int i = sb * 1024 + tid * 4;
    int v0 = (i + 0 < N) ? deg[i + 0] : 0;
    int v1 = (i + 1 < N) ? deg[i + 1] : 0;
    int v2 = (i + 2 < N) ? deg[i + 2] : 0;
    int v3 = (i + 3 < N) ? deg[i + 3] : 0;
    int tsum = v0 + v1 + v2 + v3;
    int xs = tsum;
    #pragma unroll
    for (int off = 1; off < 64; off <<= 1) {
        int y = __shfl_up(xs, off, 64);
        if (lane >= off) xs += y;
    }
    if (lane == 63) ws[wv] = xs;
    __syncthreads();
    int wprefix = 0;
    #pragma unroll
    for (int w2 = 0; w2 < 4; w2++) wprefix += (w2 < wv) ? ws[w2] : 0;
    int chunk_total = ws[0] + ws[1] + ws[2] + ws[3];

    if (tid == 0) {
        st_rel64(&lb[sb], ((u64)(unsigned)chunk_total << 2) | 1ull);
        int prefix = 0;
        for (int pred = sb - 1; pred >= 0; --pred) {
            u64 v;
            do {
                v = ld_acq64(&lb[pred]);
                if ((v & 3) == 0) __builtin_amdgcn_s_sleep(1);
            } while ((v & 3) == 0);
            prefix += (int)(unsigned)(v >> 2);
            if ((v & 3) == 2) break;
        }
        st_rel64(&lb[sb], ((u64)(unsigned)(prefix + chunk_total) << 2) | 2ull);
        s_prefix = prefix;
    }
    __syncthreads();

    int carry = s_prefix;
    int e0 = carry + wprefix + xs - tsum;
    int e1 = e0 + v0, e2 = e1 + v1, e3 = e2 + v2;
    if (i + 0 < N) { offs[i + 0] = e0; cur[i + 0] = e0; dinv[i + 0] = rsqrtf((float)(v0 + 1)); }
    if (i + 1 < N) { offs[i + 1] = e1; cur[i + 1] = e1; dinv[i + 1] = rsqrtf((float)(v1 + 1)); }
    if (i + 2 < N) { offs[i + 2] = e2; cur[i + 2] = e2; dinv[i + 2] = rsqrtf((float)(v2 + 1)); }
    if (i + 3 < N) { offs[i + 3] = e3; cur[i + 3] = e3; dinv[i + 3] = rsqrtf((float)(v3 + 1)); }
    if (sb == SB - 1 && tid == 0) offs[N] = carry + chunk_total;
}

// ---------------------------------------------------------------------------
// fillgemm: blocks [0, GB) = gemm1 (h1 = x @ W1, bf16 out);
//           blocks [GB, GB+FB) = CSR fill. Independent -> no handshake.
// ---------------------------------------------------------------------------
__global__ __launch_bounds__(256) void fillgemm_kernel(
    const float* __restrict__ x, const unsigned short* __restrict__ W1f,
    unsigned short* __restrict__ h1, int N,
    const int* __restrict__ src, const int* __restrict__ dst, int E,
    int* __restrict__ cur, const float* __restrict__ dinv,
    unsigned int* __restrict__ csr) {

    const int GB = (N + 63) / 64;
    int b = blockIdx.x;
    int tid = threadIdx.x;

    __shared__ unsigned short As[64 * 128];  // 16 KB (gemm blocks only)

    if (b >= GB) {
        // ---------------- fill ----------------
        int i = (b - GB) * 256 + tid;
        if (i < E) {
            int s = src[i];
            int d = dst[i];
            int p = atomicAdd(&cur[d], 1);
            float w = dinv[s] * dinv[d];
            csr[i >= 0 ? p : 0] = (unsigned int)s | ((unsigned int)f2bf(w) << 16);
        }
        return;
    }

    // ---------------- gemm1 ----------------
    constexpr int K = 128, BN = 128;
    int lane = tid & 63;
    int w = tid >> 6;
    int row0 = b * 64;

    short8 bfr[2][4];
    #pragma unroll
    for (int nl = 0; nl < 2; nl++)
        #pragma unroll
        for (int ks = 0; ks < 4; ks++)
            bfr[nl][ks] = *(const short8*)(W1f + ((((w * 2 + nl) * 4 + ks) * 64) + lane) * 8);

    #pragma unroll
    for (int it = 0; it < 8; it++) {
        int idx = it * 256 + tid;
        int row = idx >> 5, kq = idx & 31;
        int k0 = kq * 4;
        int ks = k0 >> 5, quad = (k0 >> 3) & 3, j0 = k0 & 7, mt = row >> 4;
        ushort4 o = make_ushort4(0, 0, 0, 0);
        int gr = row0 + row;
        if (gr < N) {
            float4 a = *(const float4*)(x + (size_t)gr * K + k0);
            o.x = f2bf(a.x); o.y = f2bf(a.y); o.z = f2bf(a.z); o.w = f2bf(a.w);
        }
        int off = (((mt * 4 + ks) * 64) + (row & 15) + 16 * quad) * 8 + j0;
        *(ushort4*)(As + off) = o;
    }
    __syncthreads();

    f32x4 acc[4][2];
    #pragma unroll
    for (int mt = 0; mt < 4; mt++)
        #pragma unroll
        for (int nl = 0; nl < 2; nl++) acc[mt][nl] = (f32x4){0.f, 0.f, 0.f, 0.f};

    #pragma unroll
    for (int ks = 0; ks < 4; ks++) {
        short8 af[4];
        #pragma unroll
        for (int mt = 0; mt < 4; mt++)
            af[mt] = *(const short8*)(As + (((mt * 4 + ks) * 64) + lane) * 8);
        #pragma unroll
        for (int mt = 0; mt < 4; mt++)
            #pragma unroll
            for (int nl = 0; nl < 2; nl++)
                acc[mt][nl] = __builtin_amdgcn_mfma_f32_16x16x32_bf16(
                    af[mt], bfr[nl][ks], acc[mt][nl], 0, 0, 0);
    }

    int col16 = lane & 15;
    int rowq = lane >> 4;
    #pragma unroll
    for (int mt = 0; mt < 4; mt++) {
        #pragma unroll
        for (int nl = 0; nl < 2; nl++) {
            int gc = (w * 2 + nl) * 16 + col16;
            #pragma unroll
            for (int r = 0; r < 4; r++) {
                int gr = row0 + mt * 16 + rowq * 4 + r;
                if (gr < N) h1[(size_t)gr * BN + gc] = f2bf(acc[mt][nl][r]);
            }
        }
    }
}

// ---------------------------------------------------------------------------
// aggmm: fused Agg(layer1) + bias + ReLU + GEMM2 (h2 = hmid @ W2, bf16).
// Block = 4 waves = 16 nodes. 32 lanes/edge x 2 edges x unroll4; shfl_xor
// combine; rows -> LDS A-frag order; 4 MFMAs per wave.
// ---------------------------------------------------------------------------
__global__ __launch_bounds__(256) void aggmm_kernel(const unsigned short* __restrict__ h1,
                                                    const int* __restrict__ offs,
                                                    const unsigned int* __restrict__ csr,
                                                    const float* __restrict__ dinv,
                                                    const float* __restrict__ b1,
                                                    const unsigned short* __restrict__ W2f,
                                                    unsigned short* __restrict__ h2,
                                                    int n) {
    __shared__ unsigned short As[4 * 64 * 8];  // 4 KB, one 16x128 A-tile

    int tid = threadIdx.x;
    int t = tid & 63;
    int w = tid >> 6;
    int p = t >> 5;
    int t5 = t & 31;
    int nodebase = blockIdx.x * 16;

    short8 bw[4];
    #pragma unroll
    for (int ks = 0; ks < 4; ks++)
        bw[ks] = *(const short8*)(W2f + (((w * 4 + ks) * 64) + t) * 8);

    float4 bias = *(const float4*)(b1 + t5 * 4);

    #pragma unroll
    for (int i = 0; i < 4; i++) {
        int row16 = w * 4 + i;
        int node = nodebase + row16;
        float a0 = 0.f, a1 = 0.f, a2 = 0.f, a3 = 0.f;
        if (node < n) {
            float di = dinv[node];
            float sw = di * di;
            if (p == 0) {
                uint2 su = *(const uint2*)(h1 + (size_t)node * 128 + t5 * 4);
                a0 = bf2f_lo(su.x) * sw; a1 = bf2f_hi(su.x) * sw;
                a2 = bf2f_lo(su.y) * sw; a3 = bf2f_hi(su.y) * sw;
            }
            int e0 = offs[node];
            int e1 = offs[node + 1];
            int iters = (e1 - e0 + 7) >> 3;
            for (int it = 0; it < iters; it++) {
                int eb = e0 + it * 8;
                #pragma unroll
                for (int j = 0; j < 4; j++) {
                    int ee = eb + j * 2 + p;
                    int ec = min(ee, e1 - 1);
                    unsigned int pk = csr[ec];
                    float wgt = (ee < e1) ? bf2f_hi(pk) : 0.f;
                    int s = pk & 0xffff;
                    uint2 hu = *(const uint2*)(h1 + (size_t)s * 128 + t5 * 4);
                    a0 += bf2f_lo(hu.x) * wgt; a1 += bf2f_hi(hu.x) * wgt;
                    a2 += bf2f_lo(hu.y) * wgt; a3 += bf2f_hi(hu.y) * wgt;
                }
            }
        }
        a0 += __shfl_xor(a0, 32, 64);
        a1 += __shfl_xor(a1, 32, 64);
        a2 += __shfl_xor(a2, 32, 64);
        a3 += __shfl_xor(a3, 32, 64);
        if (p == 0) {
            if (node < n) {
                a0 = fmaxf(a0 + bias.x, 0.f);
                a1 = fmaxf(a1 + bias.y, 0.f);
                a2 = fmaxf(a2 + bias.z, 0.f);
                a3 = fmaxf(a3 + bias.w, 0.f);
            }
            int k0 = t5 * 4;
            int ks = k0 >> 5, quad = (k0 >> 3) & 3, j0 = k0 & 7;
            ushort4 pk4 = make_ushort4(f2bf(a0), f2bf(a1), f2bf(a2), f2bf(a3));
            *(ushort4*)(As + ((ks * 64) + row16 + 16 * quad) * 8 + j0) = pk4;
        }
    }
    __syncthreads();

    f32x4 acc = (f32x4){0.f, 0.f, 0.f, 0.f};
    #pragma unroll
    for (int ks = 0; ks < 4; ks++) {
        short8 af = *(const short8*)(As + ((ks * 64) + t) * 8);
        acc = __builtin_amdgcn_mfma_f32_16x16x32_bf16(af, bw[ks], acc, 0, 0, 0);
    }

    int col = w * 16 + (t & 15);
    int rowq = t >> 4;
    #pragma unroll
    for (int r = 0; r < 4; r++) {
        int gr = nodebase + rowq * 4 + r;
        if (gr < n) h2[(size_t)gr * 64 + col] = f2bf(acc[r]);
    }
}

// ---------------------------------------------------------------------------
// aggout: Agg(layer2) + bias, fp32 out. One node/wave; 16 lanes/edge,
// 4 edges concurrent, unroll2; shfl_xor(16,32) combine; float4 epilogue.
// ---------------------------------------------------------------------------
__global__ __launch_bounds__(256) void aggout_kernel(const unsigned short* __restrict__ h2,
                                                     const int* __restrict__ offs,
                                                     const unsigned int* __restrict__ csr,
                                                     const float* __restrict__ dinv,
                                                     const float* __restrict__ b2,
                                                     float* __restrict__ out, int n) {
    int tid = threadIdx.x;
    int t = tid & 63;
    int w = tid >> 6;
    int node = blockIdx.x * 4 + w;
    if (node >= n) return;
    int p = t >> 4;
    int t4 = t & 15;

    float a0 = 0.f, a1 = 0.f, a2 = 0.f, a3 = 0.f;
    float di = dinv[node];
    float sw = di * di;
    if (p == 0) {
        uint2 su = *(const uint2*)(h2 + (size_t)node * 64 + t4 * 4);
        a0 = bf2f_lo(su.x) * sw; a1 = bf2f_hi(su.x) * sw;
        a2 = bf2f_lo(su.y) * sw; a3 = bf2f_hi(su.y) * sw;
    }

    int e0 = offs[node];
    int e1 = offs[node + 1];
    int iters = (e1 - e0 + 7) >> 3;
    for (int it = 0; it < iters; it++) {
        int eb = e0 + it * 8;
        #pragma unroll
        for (int j = 0; j < 2; j++) {
            int ee = eb + j * 4 + p;
            int ec = min(ee, e1 - 1);
            unsigned int pk = csr[ec];
            float wgt = (ee < e1) ? bf2f_hi(pk) : 0.f;
            int s = pk & 0xffff;
            uint2 hu = *(const uint2*)(h2 + (size_t)s * 64 + t4 * 4);
            a0 += bf2f_lo(hu.x) * wgt; a1 += bf2f_hi(hu.x) * wgt;
            a2 += bf2f_lo(hu.y) * wgt; a3 += bf2f_hi(hu.y) * wgt;
        }
    }
    a0 += __shfl_xor(a0, 16, 64); a1 += __shfl_xor(a1, 16, 64);
    a2 += __shfl_xor(a2, 16, 64); a3 += __shfl_xor(a3, 16, 64);
    a0 += __shfl_xor(a0, 32, 64); a1 += __shfl_xor(a1, 32, 64);
    a2 += __shfl_xor(a2, 32, 64); a3 += __shfl_xor(a3, 32, 64);
    if (p == 0) {
        float4 bb = *(const float4*)(b2 + t4 * 4);
        *(float4*)(out + (size_t)node * 64 + t4 * 4) =
            make_float4(a0 + bb.x, a1 + bb.y, a2 + bb.z, a3 + bb.w);
    }
}

extern "C" void kernel_launch(void* const* d_in, const int* in_sizes, int n_in,
                              void* d_out, int out_size, void* d_ws, size_t ws_size,
                              hipStream_t stream) {
    const float* x  = (const float*)d_in[0];
    const int*   ei = (const int*)d_in[1];
    const float* W1 = (const float*)d_in[2];
    const float* b1 = (const float*)d_in[3];
    const float* W2 = (const float*)d_in[4];
    const float* b2 = (const float*)d_in[5];

    const int N = in_sizes[0] / 128;   // 50000
    const int E = in_sizes[1] / 2;     // 500000
    const int* src = ei;
    const int* dst = ei + E;

    char* p = (char*)d_ws;
    auto alloc = [&](size_t bytes) {
        char* r = p;
        p += (bytes + 255) & ~(size_t)255;
        return r;
    };
    int*   degi  = (int*)  alloc((size_t)N * 4);
    float* dinv  = (float*)alloc((size_t)N * 4);
    int*   offs  = (int*)  alloc((size_t)(N + 1) * 4);
    int*   cur   = (int*)  alloc((size_t)N * 4);
    u64*   lb    = (u64*)  alloc((size_t)64 * 8);
    unsigned int*   csr  = (unsigned int*)alloc((size_t)E * 4);
    unsigned short* W1f  = (unsigned short*)alloc((size_t)128 * 128 * 2);
    unsigned short* W2f  = (unsigned short*)alloc((size_t)64 * 128 * 2);
    unsigned short* h1   = (unsigned short*)alloc((size_t)N * 128 * 2);
    unsigned short* h2   = (unsigned short*)alloc((size_t)N * 64 * 2);
    float* out = (float*)d_out;

    const int GB = (N + 63) / 64;        // 782
    const int FB = (E + 255) / 256;      // 1954
    const int SB = (N + 1023) / 1024;    // 49

    init_kernel<<<(N + 255) / 256, 256, 0, stream>>>(W1, W2, W1f, W2f, degi, lb, N);
    count_kernel<<<FB, 256, 0, stream>>>(dst, E, degi);
    scan_lb_kernel<<<SB, 256, 0, stream>>>(degi, N, lb, offs, cur, dinv);
    fillgemm_kernel<<<GB + FB, 256, 0, stream>>>(x, W1f, h1, N, src, dst, E,
                                                 cur, dinv, csr);
    aggmm_kernel<<<(N + 15) / 16, 256, 0, stream>>>(h1, offs, csr, dinv, b1, W2f, h2, N);
    aggout_kernel<<<(N + 3) / 4, 256, 0, stream>>>(h2, offs, csr, dinv, b2, out, N);
}